// Round 1
// baseline (62.202 us; speedup 1.0000x reference)
//
#include <hip/hip_runtime.h>

// MultiviewFeatureFusion: features (32768, 2048) f32, pids (32768,) int
//   fusion_features = features.reshape(8192, 4, 2048).sum(axis=1)  -> (8192, 2048) f32
//   fusion_pids     = pids[::4].astype(float32)                    -> (8192,)      f32
// d_out = [fusion_features flat | fusion_pids], 8192*2048 + 8192 floats.

#define VIEW_NUM 4
#define N_ROWS   32768
#define CDIM     2048
#define CHUNK    (N_ROWS / VIEW_NUM)   // 8192
#define C4       (CDIM / 4)            // 512 float4 per row

__global__ __launch_bounds__(256)
void MultiviewFeatureFusion_kernel(const float4* __restrict__ feat,
                                   const int*    __restrict__ pids,
                                   float4*       __restrict__ out_feat,
                                   float*        __restrict__ out_pids) {
    const int v = blockIdx.x * blockDim.x + threadIdx.x;   // output float4 index
    const int row  = v >> 9;          // v / C4
    const int col4 = v & (C4 - 1);    // v % C4

    const float4* p = feat + ((size_t)row * VIEW_NUM) * C4 + col4;
    float4 a = p[0];
    float4 b = p[C4];
    float4 c = p[2 * C4];
    float4 d = p[3 * C4];

    float4 s;
    s.x = (a.x + b.x) + (c.x + d.x);
    s.y = (a.y + b.y) + (c.y + d.y);
    s.z = (a.z + b.z) + (c.z + d.z);
    s.w = (a.w + b.w) + (c.w + d.w);
    out_feat[v] = s;

    if (v < CHUNK) {
        out_pids[v] = (float)pids[v * VIEW_NUM];
    }
}

extern "C" void kernel_launch(void* const* d_in, const int* in_sizes, int n_in,
                              void* d_out, int out_size, void* d_ws, size_t ws_size,
                              hipStream_t stream) {
    const float4* feat = (const float4*)d_in[0];
    const int*    pids = (const int*)d_in[1];

    float4* out_feat = (float4*)d_out;
    float*  out_pids = (float*)d_out + (size_t)CHUNK * CDIM;

    const int total_v4 = CHUNK * C4;            // 4,194,304
    const int block = 256;
    const int grid  = total_v4 / block;         // 16,384

    MultiviewFeatureFusion_kernel<<<grid, block, 0, stream>>>(feat, pids, out_feat, out_pids);
}